// Round 7
// baseline (336.784 us; speedup 1.0000x reference)
//
#include <hip/hip_runtime.h>
#include <hip/hip_bf16.h>

#define IN_C 192
#define HW   9600     // 80*120
#define NPIX 128      // pixels per tile (8 waves x 16-px strips)
#define NT_PER_B 75   // tiles per batch image (9600/128)
#define NTILES 1200   // 75 * 16
#define NBLK 512      // 2 blocks/CU x 256 CU

typedef __attribute__((ext_vector_type(8))) short bf16x8;
typedef __attribute__((ext_vector_type(4))) float f32x4;

static __device__ __forceinline__ short f2bf(float f) {
  return __builtin_bit_cast(short, __float2bfloat16(f));   // RNE
}

// Persistent-ish fused kernel. R6 kept (validated): W in LDS (lgkmcnt stream)
// so the K-loop's ONLY vmcnt ops are x prefetches; depth-2 register rotation;
// no barriers in the K-loop; x read exactly once. New in R7:
//  - W packed in-kernel (fp32->bf16 fragment layout, once per block, L3-served)
//  - bias staged to LDS (epilogue global bias loads would FIFO-drain the
//    x prefetch, R5 mechanism)
//  - 512 blocks x 2-3 tiles each; prefetch rotation (period 3, 6 steps/tile)
//    carries across tiles: steps 4/5 prefetch next tile's k0/k1 -> the vmcnt
//    FIFO never drains between block start and block end.
__global__ __launch_bounds__(512, 4) void conv_mfma_kernel(
    const float* __restrict__ x, const float* __restrict__ W,
    const float* __restrict__ bias, float* __restrict__ out) {
  __shared__ short wl[12 * 6 * 64 * 8];   // 73728 B packed-fragment W
  __shared__ float bl[192];

  const int tid  = threadIdx.x;
  const int wid  = tid >> 6;
  const int lane = tid & 63;
  const int c    = lane & 15;
  const int g    = lane >> 4;
  const int bid  = blockIdx.x;

  // ---- Prologue: pack W fp32 -> bf16 fragments in LDS; bias -> LDS ----
  // chunk -> (fo, kk, l): lane l of frag (fo,kk) holds o = fo*16+(l&15),
  // k = kk*32+(l>>4)*8+j (same k(l,j) convention as the x B-frags; any true
  // intra-fragment k-permutation cancels — validated R1).
#pragma unroll
  for (int i = 0; i < 9; ++i) {
    const int chunk = i * 512 + tid;     // 0..4607
    const int fo  = chunk / (6 * 64);
    const int rem = chunk % (6 * 64);
    const int kk  = rem / 64;
    const int l   = rem & 63;
    const int o   = fo * 16 + (l & 15);
    const int kb  = kk * 32 + (l >> 4) * 8;
    bf16x8 v;
#pragma unroll
    for (int j = 0; j < 8; ++j) v[j] = f2bf(W[o * IN_C + kb + j]);
    *reinterpret_cast<bf16x8*>(wl + (size_t)chunk * 8) = v;
  }
  if (tid < 192) bl[tid] = bias[tid];
  __syncthreads();   // W+bias staged; everything below is barrier-free

  // Tiles for this block: bid, bid+512, (bid+1024 if bid<176). Three-tile
  // blocks land on distinct CUs (round-robin) -> per-CU work 5 vs 4 tiles.
  int t_cur = bid;
  const int ntiles = (bid < NTILES - 2 * NBLK) ? 3 : 2;

  // x pointer for tile t, this lane: k = kk*32 + g*8 + j -> xp[(kk*32+j)*HW]
#define XPTR(T)                                                       \
  (x + (size_t)((T) / NT_PER_B) * (IN_C * HW)                         \
     + ((T) % NT_PER_B) * NPIX + (size_t)(g * 8) * HW + wid * 16 + c)

#define LOADX(DST, PTR, KK)                                           \
  { _Pragma("unroll")                                                 \
    for (int j = 0; j < 8; ++j)                                       \
      DST[j] = (PTR)[(size_t)((KK) * 32 + j) * HW]; }

  // KSTEP: optional prefetch (from PFPTR, k-step PFKK) then consume CURB at
  // k-step KK. af from LDS in batches of 3 (12 transient VGPRs).
#define KSTEP(CURB, PFB, PFPTR, PFKK, PFEN, KK)                       \
  {                                                                   \
    if (PFEN) { LOADX(PFB, PFPTR, PFKK); }                            \
    bf16x8 bfr;                                                       \
    _Pragma("unroll")                                                 \
    for (int j = 0; j < 8; ++j) bfr[j] = f2bf(CURB[j]);               \
    _Pragma("unroll")                                                 \
    for (int h = 0; h < 4; ++h) {                                     \
      bf16x8 af[3];                                                   \
      _Pragma("unroll")                                               \
      for (int m = 0; m < 3; ++m)                                     \
        af[m] = *reinterpret_cast<const bf16x8*>(                     \
            wl + (size_t)((((h * 3 + m) * 6 + (KK)) * 64) + lane) * 8); \
      _Pragma("unroll")                                               \
      for (int m = 0; m < 3; ++m)                                     \
        acc[h * 3 + m] = __builtin_amdgcn_mfma_f32_16x16x32_bf16(     \
            af[m], bfr, acc[h * 3 + m], 0, 0, 0);                     \
    }                                                                 \
  }

  const float* xp = XPTR(t_cur);
  float xa[8], xb_[8], xc[8];
  LOADX(xa, xp, 0);
  LOADX(xb_, xp, 1);

  for (int it = 0; it < ntiles; ++it) {
    const int t_nxt = t_cur + NBLK;
    const bool haveNext = (it + 1 < ntiles);
    const float* xn = haveNext ? XPTR(t_nxt) : xp;

    f32x4 acc[12];
#pragma unroll
    for (int m = 0; m < 12; ++m) acc[m] = (f32x4)0.0f;

    // consume k0..k5 (xa,xb_,xc rotation, period 3 = exact over 6 steps);
    // steps 4/5 prefetch the NEXT tile's k0/k1 -> seamless pipeline.
    KSTEP(xa,  xc,  xp, 2, true,     0);
    KSTEP(xb_, xa,  xp, 3, true,     1);
    KSTEP(xc,  xb_, xp, 4, true,     2);
    KSTEP(xa,  xc,  xp, 5, true,     3);
    KSTEP(xb_, xa,  xn, 0, haveNext, 4);
    KSTEP(xc,  xb_, xn, 1, haveNext, 5);

    // Epilogue: C/D col = lane&15 (pixel, == c), row = g*4 + r (out-ch).
    // bias from LDS (a global bias load here would FIFO-drain the prefetch).
    const int tb = t_cur / NT_PER_B;
    const int p  = (t_cur % NT_PER_B) * NPIX + wid * 16 + c;
    const int hi = p / 120;
    const int wi = p - hi * 120;
#pragma unroll
    for (int mo = 0; mo < 12; ++mo) {
      const int ob = mo * 16 + g * 4;
      const f32x4 bv = *reinterpret_cast<const f32x4*>(bl + ob);
      const f32x4 v  = acc[mo];
#pragma unroll
      for (int r = 0; r < 4; ++r) {
        const int o  = ob + r;
        const int co = o >> 6;
        const int br = (o >> 3) & 7;
        const int bc = o & 7;
        const int idx = ((tb * 3 + co) * 640 + br * 80 + hi) * 960 + bc * 120 + wi;
        out[idx] = v[r] + bv[r];
      }
    }

    t_cur = t_nxt;
    xp = xn;
  }
#undef KSTEP
#undef LOADX
#undef XPTR
}

extern "C" void kernel_launch(void* const* d_in, const int* in_sizes, int n_in,
                              void* d_out, int out_size, void* d_ws, size_t ws_size,
                              hipStream_t stream) {
  const float* x    = (const float*)d_in[0];
  const float* W    = (const float*)d_in[1];
  const float* bias = (const float*)d_in[2];
  float* out = (float*)d_out;

  conv_mfma_kernel<<<NBLK, 512, 0, stream>>>(x, W, bias, out);
}

// Round 8
// 56.443 us; speedup vs baseline: 5.9668x; 5.9668x over previous
//
#include <hip/hip_runtime.h>
#include <hip/hip_bf16.h>

#define IN_C 192
#define HW   9600     // 80*120
#define NPIX 128      // pixels per tile (8 waves x 16-px strips)
#define NT_PER_B 75   // tiles per batch image (9600/128)
#define NTILES 1200   // 75 * 16
#define NBLK 512      // 2 blocks/CU x 256 CU -> single dispatch round
#define NEXTRA (3 * NBLK - NTILES)   // 336 blocks run a dummy 3rd body

typedef __attribute__((ext_vector_type(8))) short bf16x8;
typedef __attribute__((ext_vector_type(4))) float f32x4;

static __device__ __forceinline__ short f2bf(float f) {
  return __builtin_bit_cast(short, __float2bfloat16(f));   // RNE
}

// Single-dispatch fused kernel, fully straight-line (R7 lesson: a runtime
// tile loop with conditional buffer defs spills ~3KB/thread to scratch).
// Kept from R6 (validated): W packed bf16 in LDS (lgkmcnt stream) so the
// K-steps' ONLY vmcnt ops are x prefetches; depth-2 period-3 register
// rotation; no barriers after the prologue; x read exactly once from HBM.
// 512 blocks x exactly 3 static bodies; bid >= 176 re-runs tile bid+512 as a
// dummy (reads are L3 hits - x fits in 256MB L3 - stores predicated off).
__global__ __launch_bounds__(512, 4) void conv_mfma_kernel(
    const float* __restrict__ x, const float* __restrict__ W,
    const float* __restrict__ bias, float* __restrict__ out) {
  __shared__ short wl[12 * 6 * 64 * 8];   // 73728 B packed-fragment W
  __shared__ float bl[192];

  const int tid  = threadIdx.x;
  const int wid  = tid >> 6;
  const int lane = tid & 63;
  const int c    = lane & 15;
  const int g    = lane >> 4;
  const int bid  = blockIdx.x;

  // ---- Prologue: pack W fp32 -> bf16 fragments in LDS; bias -> LDS ----
  // frag (fo,kk), lane l: o = fo*16+(l&15), k = kk*32+(l>>4)*8+j (same k(l,j)
  // convention as the x B-frags; intra-fragment k-permutation cancels - R1).
#pragma unroll
  for (int i = 0; i < 9; ++i) {
    const int chunk = i * 512 + tid;     // 0..4607
    const int fo  = chunk / (6 * 64);
    const int rem = chunk % (6 * 64);
    const int kk  = rem / 64;
    const int l   = rem & 63;
    const int o   = fo * 16 + (l & 15);
    const int kb  = kk * 32 + (l >> 4) * 8;
    bf16x8 v;
#pragma unroll
    for (int j = 0; j < 8; ++j) v[j] = f2bf(W[o * IN_C + kb + j]);
    *reinterpret_cast<bf16x8*>(wl + (size_t)chunk * 8) = v;
  }
  if (tid < 192) bl[tid] = bias[tid];
  __syncthreads();   // W+bias staged; everything below is barrier-free

  const int  t0    = bid;
  const int  t1    = bid + NBLK;
  const bool third = (bid < NTILES - 2 * NBLK);      // 176 blocks
  const int  t2    = third ? bid + 2 * NBLK : t1;    // dummy: redo t1 (L3-hot)

  // x pointer for tile t, this lane: k = kk*32 + g*8 + j -> ptr[(kk*32+j)*HW]
#define XPTR(T)                                                       \
  (x + (size_t)((T) / NT_PER_B) * (IN_C * HW)                         \
     + ((T) % NT_PER_B) * NPIX + (size_t)(g * 8) * HW + wid * 16 + c)

#define LOADX(DST, PTR, KK)                                           \
  { _Pragma("unroll")                                                 \
    for (int j = 0; j < 8; ++j)                                       \
      DST[j] = (PTR)[(size_t)((KK) * 32 + j) * HW]; }

  // KSTEP: prefetch (compile-time enable) then consume CURB at k-step KK.
  // af from LDS in batches of 3 (12 transient VGPRs).
#define KSTEP(CURB, PFB, PFPTR, PFKK, PFEN, KK)                       \
  {                                                                   \
    if (PFEN) { LOADX(PFB, PFPTR, PFKK); }                            \
    bf16x8 bfr;                                                       \
    _Pragma("unroll")                                                 \
    for (int j = 0; j < 8; ++j) bfr[j] = f2bf(CURB[j]);               \
    _Pragma("unroll")                                                 \
    for (int h = 0; h < 4; ++h) {                                     \
      bf16x8 af[3];                                                   \
      _Pragma("unroll")                                               \
      for (int m = 0; m < 3; ++m)                                     \
        af[m] = *reinterpret_cast<const bf16x8*>(                     \
            wl + (size_t)((((h * 3 + m) * 6 + (KK)) * 64) + lane) * 8); \
      _Pragma("unroll")                                               \
      for (int m = 0; m < 3; ++m)                                     \
        acc[h * 3 + m] = __builtin_amdgcn_mfma_f32_16x16x32_bf16(     \
            af[m], bfr, acc[h * 3 + m], 0, 0, 0);                     \
    }                                                                 \
  }

  // BODY: 6 K-steps on tile T (rotation returns to start alignment after 6),
  // steps 4/5 prefetch NXTP's k0/k1 (PFNEXT is compile-time), then epilogue.
#define BODY(T, CURP, NXTP, PFNEXT, STOREOK)                          \
  {                                                                   \
    f32x4 acc[12];                                                    \
    _Pragma("unroll")                                                 \
    for (int m = 0; m < 12; ++m) acc[m] = (f32x4)0.0f;                \
    KSTEP(xa,  xc,  CURP, 2, true,   0);                              \
    KSTEP(xb_, xa,  CURP, 3, true,   1);                              \
    KSTEP(xc,  xb_, CURP, 4, true,   2);                              \
    KSTEP(xa,  xc,  CURP, 5, true,   3);                              \
    KSTEP(xb_, xa,  NXTP, 0, PFNEXT, 4);                              \
    KSTEP(xc,  xb_, NXTP, 1, PFNEXT, 5);                              \
    if (STOREOK) {                                                    \
      const int tb = (T) / NT_PER_B;                                  \
      const int p  = ((T) % NT_PER_B) * NPIX + wid * 16 + c;          \
      const int hi = p / 120;                                         \
      const int wi = p - hi * 120;                                    \
      _Pragma("unroll")                                               \
      for (int mo = 0; mo < 12; ++mo) {                               \
        const int ob = mo * 16 + g * 4;                               \
        const f32x4 bv = *reinterpret_cast<const f32x4*>(bl + ob);    \
        const f32x4 v  = acc[mo];                                     \
        _Pragma("unroll")                                             \
        for (int r = 0; r < 4; ++r) {                                 \
          const int o  = ob + r;                                      \
          const int co = o >> 6;                                      \
          const int br = (o >> 3) & 7;                                \
          const int bc = o & 7;                                       \
          const int idx = ((tb * 3 + co) * 640 + br * 80 + hi) * 960  \
                          + bc * 120 + wi;                            \
          out[idx] = v[r] + bv[r];                                    \
        }                                                             \
      }                                                               \
    }                                                                 \
  }

  const float* xp0 = XPTR(t0);
  const float* xp1 = XPTR(t1);
  const float* xp2 = XPTR(t2);

  float xa[8], xb_[8], xc[8];
  LOADX(xa, xp0, 0);
  LOADX(xb_, xp0, 1);

  BODY(t0, xp0, xp1, true,  true);
  BODY(t1, xp1, xp2, true,  true);
  BODY(t2, xp2, xp2, false, third);

#undef BODY
#undef KSTEP
#undef LOADX
#undef XPTR
}

extern "C" void kernel_launch(void* const* d_in, const int* in_sizes, int n_in,
                              void* d_out, int out_size, void* d_ws, size_t ws_size,
                              hipStream_t stream) {
  const float* x    = (const float*)d_in[0];
  const float* W    = (const float*)d_in[1];
  const float* bias = (const float*)d_in[2];
  float* out = (float*)d_out;

  conv_mfma_kernel<<<NBLK, 512, 0, stream>>>(x, W, bias, out);
}

// Round 9
// 50.288 us; speedup vs baseline: 6.6972x; 1.1224x over previous
//
#include <hip/hip_runtime.h>
#include <hip/hip_bf16.h>

#define IN_C 192
#define HW   9600   // 80*120
#define NPIX 128    // pixels per block (8 waves x 16-px strips)

typedef __attribute__((ext_vector_type(8))) short bf16x8;
typedef __attribute__((ext_vector_type(4))) float f32x4;

static __device__ __forceinline__ short f2bf(float f) {
  return __builtin_bit_cast(short, __float2bfloat16(f));   // RNE
}

// Pack W (192x192 fp32, row-major [o][k]) into fragment-sequential bf16:
// frag (fo, kk): 64 lanes x 8 bf16 (16B/lane), lane l -> o = fo*16 + (l&15),
// k = kk*32 + (l>>4)*8 + j. Same k(l,j) convention as the x B-frags, so any
// true intra-fragment k-permutation of the HW layout cancels (validated R1).
__global__ void pack_w_kernel(const float* __restrict__ W, short* __restrict__ wp) {
  int idx = blockIdx.x * 256 + threadIdx.x;   // 0 .. 12*6*64-1 = 4607
  if (idx >= 12 * 6 * 64) return;
  int fo  = idx / (6 * 64);
  int rem = idx % (6 * 64);
  int kk  = rem / 64;
  int l   = rem % 64;
  int o   = fo * 16 + (l & 15);
  int kb  = kk * 32 + (l >> 4) * 8;
  bf16x8 v;
#pragma unroll
  for (int j = 0; j < 8; ++j) v[j] = f2bf(W[o * IN_C + kb + j]);
  *reinterpret_cast<bf16x8*>(wp + (size_t)idx * 8) = v;
}

// Per-pixel GEMM D[o][p] = sum_k W[o][k]*x[b][k][p] + bias[o], sub-block scatter.
// R6 structure (best measured: 49us) + two micro-fixes:
//  - depth-3 x prefetch: 4 named buffers (A:k0,k4 B:k1,k5 C:k2 D:k3); every
//    consume-wait has a 3-K-step (~1100cy) lead > ~900cy HBM latency.
//  - k0..k2 x loads issued BEFORE the W staging burst + barrier, hiding the
//    initial HBM latency under the W prologue.
// Invariants kept (R5/R6 validated): W lives in LDS via global_load_lds
// (lgkmcnt consumer stream) so the K-loop's ONLY vmcnt ops are x prefetches;
// no barriers after the prologue; x read exactly once; bias loads are
// epilogue-only (post-MFMA, can't FIFO-drain the prefetch).
__global__ __launch_bounds__(512, 4) void conv_mfma_kernel(
    const float* __restrict__ x, const short* __restrict__ wp,
    const float* __restrict__ bias, float* __restrict__ out) {
  __shared__ short wl[12 * 6 * 64 * 8];   // 73728 B packed-fragment W

  const int tid  = threadIdx.x;
  const int wid  = tid >> 6;
  const int lane = tid & 63;
  const int c    = lane & 15;
  const int g    = lane >> 4;
  const int b    = blockIdx.y;
  const int p    = blockIdx.x * NPIX + wid * 16 + c;   // this lane's pixel

  // lane's x column base: k = kk*32 + g*8 + j  ->  xp[(kk*32 + j)*HW]
  const float* xp = x + (size_t)b * IN_C * HW + (size_t)(g * 8) * HW + p;

  float xA[8], xB[8], xC[8], xD[8];

#define LOADX(DST, KK)                                                \
  { _Pragma("unroll")                                                 \
    for (int j = 0; j < 8; ++j)                                       \
      DST[j] = xp[(size_t)((KK) * 32 + j) * HW]; }

  // ---- Prologue: x k0..k2 first (long HBM latency), then W -> LDS ----
  LOADX(xA, 0);
  LOADX(xB, 1);
  LOADX(xC, 2);
#pragma unroll
  for (int i = 0; i < 9; ++i) {
    const int chunk = i * 512 + tid;     // 0..4607
    const short* src = wp + (size_t)chunk * 8;
    short* dst = wl + (size_t)chunk * 8;
    __builtin_amdgcn_global_load_lds(
        (const __attribute__((address_space(1))) void*)src,
        (__attribute__((address_space(3))) void*)dst, 16, 0, 0);
  }
  __syncthreads();   // drains W staging (and the x loads); K-loop barrier-free

  f32x4 acc[12];
#pragma unroll
  for (int m = 0; m < 12; ++m) acc[m] = (f32x4)0.0f;

  // af from LDS in batches of 3 (12 transient VGPRs) to bound pressure.
#define KSTEP(CURB, PFB, PFKK, PFEN, KK)                              \
  {                                                                   \
    if (PFEN) { LOADX(PFB, PFKK); }                                   \
    bf16x8 bfr;                                                       \
    _Pragma("unroll")                                                 \
    for (int j = 0; j < 8; ++j) bfr[j] = f2bf(CURB[j]);               \
    _Pragma("unroll")                                                 \
    for (int h = 0; h < 4; ++h) {                                     \
      bf16x8 af[3];                                                   \
      _Pragma("unroll")                                               \
      for (int m = 0; m < 3; ++m)                                     \
        af[m] = *reinterpret_cast<const bf16x8*>(                     \
            wl + (size_t)((((h * 3 + m) * 6 + (KK)) * 64) + lane) * 8); \
      _Pragma("unroll")                                               \
      for (int m = 0; m < 3; ++m)                                     \
        acc[h * 3 + m] = __builtin_amdgcn_mfma_f32_16x16x32_bf16(     \
            af[m], bfr, acc[h * 3 + m], 0, 0, 0);                     \
    }                                                                 \
  }

  KSTEP(xA, xD, 3, true,  0);   // consume k0, prefetch k3 (3-step lead)
  KSTEP(xB, xA, 4, true,  1);   // consume k1, prefetch k4
  KSTEP(xC, xB, 5, true,  2);   // consume k2, prefetch k5
  KSTEP(xD, xA, 0, false, 3);   // consume k3 (waits vmcnt(16))
  KSTEP(xA, xB, 0, false, 4);   // consume k4 (waits vmcnt(8))
  KSTEP(xB, xC, 0, false, 5);   // consume k5 (waits vmcnt(0))
#undef KSTEP
#undef LOADX

  // Epilogue: C/D col = lane&15 (pixel, == c), row = g*4 + r (out-ch).
  const int hi = p / 120;
  const int wi = p - hi * 120;
#pragma unroll
  for (int mo = 0; mo < 12; ++mo) {
    const int ob = mo * 16 + g * 4;
    const f32x4 bv = *reinterpret_cast<const f32x4*>(bias + ob);
    const f32x4 v  = acc[mo];
#pragma unroll
    for (int r = 0; r < 4; ++r) {
      const int o  = ob + r;
      const int co = o >> 6;
      const int br = (o >> 3) & 7;
      const int bc = o & 7;
      const int idx = ((b * 3 + co) * 640 + br * 80 + hi) * 960 + bc * 120 + wi;
      out[idx] = v[r] + bv[r];
    }
  }
}

extern "C" void kernel_launch(void* const* d_in, const int* in_sizes, int n_in,
                              void* d_out, int out_size, void* d_ws, size_t ws_size,
                              hipStream_t stream) {
  const float* x    = (const float*)d_in[0];
  const float* W    = (const float*)d_in[1];
  const float* bias = (const float*)d_in[2];
  float* out = (float*)d_out;
  short* wp  = (short*)d_ws;   // 192*192 bf16 packed-fragment W (73728 B)

  pack_w_kernel<<<18, 256, 0, stream>>>(W, wp);
  dim3 grid(75, 16);  // 75 pixel tiles of 128 (9600 exact), 16 batches
  conv_mfma_kernel<<<grid, 512, 0, stream>>>(x, wp, bias, out);
}